// Round 5
// baseline (138.958 us; speedup 1.0000x reference)
//
#include <hip/hip_runtime.h>
#include <hip/hip_bf16.h>

#define WB 8192
#define WD 128
#define WC 100
#define NSPLIT 32
#define JSPL (WB/NSPLIT)   // 256 j per split
#define NTT (JSPL/16)      // 16 j-steps of 16 rows
#define NCS 64             // class-sum blocks (128 rows each)

typedef __attribute__((ext_vector_type(8))) short short8v;
typedef __attribute__((ext_vector_type(4))) float float4v;

#define SQS 3.798282f                 // sqrt((1/TAU)/ln2): fold scale into bf16 z
#define LN2F 0.69314718055994531f

#define EXP2(x) __builtin_amdgcn_exp2f(x)
#define LOG2(x) __builtin_amdgcn_logf(x)

// ---- workspace layout (bytes) ----
#define WS_ZBF   0u          // bf16 z (pre-scaled): 2097152
#define WS_S     2097152u    // S[100][128] f32 = 51200
#define WS_CNT   2148352u    // cnt[128] int
#define WS_CNTP  2148864u    // cntpart[64][128] int = 32768
#define WS_ACC   2181632u    // accf(f32), accn(i32), ticket(i32)
#define WS_RMAX  2181888u    // rowmax keys, 8192 uint = 32768
#define WS_PART  2214656u    // union: Spart[64][12800] f32 (3276800) / part[32][8192] f32 (1048576)

__device__ __forceinline__ unsigned short f2bf(float x){
  unsigned u = __float_as_uint(x);
  u += 0x7fffu + ((u>>16)&1u);      // RNE
  return (unsigned short)(u>>16);
}
// order-preserving float<->uint key for atomicMax
__device__ __forceinline__ unsigned fkey(float x){
  unsigned u = __float_as_uint(x);
  return (u>>31) ? ~u : (u | 0x80000000u);
}
__device__ __forceinline__ float fkeyinv(unsigned k){
  return (k>>31) ? __uint_as_float(k & 0x7FFFFFFFu) : __uint_as_float(~k);
}

// blocks 0..511: convert+prescale z->bf16 (+init rmax/acc); 512..575: class sums
__global__ __launch_bounds__(256) void k_prep(const float* __restrict__ z,
                                              const int* __restrict__ labels,
                                              unsigned short* __restrict__ zbf,
                                              float* __restrict__ Spart,
                                              int* __restrict__ cntpart,
                                              unsigned* __restrict__ rmax,
                                              float* accf, int* accn, int* ticket){
  __shared__ float sacc[WC*WD];
  __shared__ int slab[128];
  __shared__ int slcnt[WC];
  const int bid = blockIdx.x, t = threadIdx.x;
  if (bid < 512){
    int idx = bid*256 + t;
    const float4* zi = (const float4*)z;
    float4 a = zi[idx*2], b = zi[idx*2+1];
    uint4 o;
    o.x = (unsigned)f2bf(a.x*SQS) | ((unsigned)f2bf(a.y*SQS)<<16);
    o.y = (unsigned)f2bf(a.z*SQS) | ((unsigned)f2bf(a.w*SQS)<<16);
    o.z = (unsigned)f2bf(b.x*SQS) | ((unsigned)f2bf(b.y*SQS)<<16);
    o.w = (unsigned)f2bf(b.z*SQS) | ((unsigned)f2bf(b.w*SQS)<<16);
    ((uint4*)zbf)[idx] = o;
    if (idx < WB) rmax[idx] = 0u;                  // key 0 < any real key
    if (bid == 0 && t == 0){ accf[0] = 0.f; accn[0] = 0; ticket[0] = 0; }
    return;
  }
  // class-sum slab: rows [cb*128, +128)
  const int cb = bid - 512;
  const int rowBase = cb*128;
  for (int i = t; i < WC*WD; i += 256) sacc[i] = 0.f;
  if (t < WC) slcnt[t] = 0;
  if (t < 128) slab[t] = labels[rowBase + t];
  __syncthreads();
  const int col = t & 127, half = t >> 7;
  #pragma unroll 4
  for (int r = 0; r < 64; r++){
    int row = half*64 + r;
    atomicAdd(&sacc[slab[row]*WD + col], z[(size_t)(rowBase+row)*WD + col]);
  }
  if (t < 128) atomicAdd(&slcnt[slab[t]], 1);
  __syncthreads();
  float* slabout = Spart + (size_t)cb*(WC*WD);
  for (int i = t; i < WC*WD; i += 256) slabout[i] = sacc[i];
  if (t < WC) cntpart[cb*128 + t] = slcnt[t];
}

// pass A: row max. blocks 0..1023: (anchorblk = bid>>5, split = bid&31);
// blocks 1024..1073: reduce Spart->S and cntpart->cnt.
__global__ __launch_bounds__(256) void k_lseA(const unsigned short* __restrict__ zbf,
                                              unsigned* __restrict__ rmax,
                                              const float* __restrict__ Spart,
                                              float* __restrict__ S,
                                              const int* __restrict__ cntpart,
                                              int* __restrict__ cnt){
  const int bid = blockIdx.x, t = threadIdx.x;
  if (bid >= 1024){
    int i = (bid-1024)*256 + t;                    // 50*256 = 12800 exactly
    float s = 0.f;
    #pragma unroll 8
    for (int b = 0; b < NCS; b++) s += Spart[(size_t)b*(WC*WD) + i];
    S[i] = s;
    if (bid == 1024 && t < WC){
      int c = 0;
      #pragma unroll 8
      for (int b = 0; b < NCS; b++) c += cntpart[b*128 + t];
      cnt[t] = c;
    }
    return;
  }
  const int wv = t>>6, lane = t&63;
  const int awave = (bid>>5)*256 + wv*64;
  const int split = bid & 31;
  const int j0 = split*JSPL;
  const int lg = lane>>4, ln = lane&15;

  short8v bf[4][4];
  #pragma unroll
  for (int ss = 0; ss < 4; ss++){
    const unsigned short* zr = zbf + (size_t)(awave + ss*16 + ln)*WD;
    #pragma unroll
    for (int kk = 0; kk < 4; kk++)
      bf[ss][kk] = *(const short8v*)(zr + kk*32 + lg*8);
  }
  float rm[4];
  #pragma unroll
  for (int ss = 0; ss < 4; ss++) rm[ss] = -INFINITY;

  const unsigned short* ap = zbf + (size_t)(j0+ln)*WD + lg*8;
  short8v afA[4], afB[4];
#define LOADA(dst, tt) { const unsigned short* p_ = ap + (size_t)(tt)*16*WD; \
    dst[0] = *(const short8v*)(p_);      dst[1] = *(const short8v*)(p_+32);  \
    dst[2] = *(const short8v*)(p_+64);   dst[3] = *(const short8v*)(p_+96); }
#define CMAX(af, tt) { \
    const int jb = j0 + (tt)*16; \
    _Pragma("unroll") \
    for (int ss = 0; ss < 4; ss++){ \
      float4v acc = {0.f,0.f,0.f,0.f}; \
      _Pragma("unroll") \
      for (int kk = 0; kk < 4; kk++) \
        acc = __builtin_amdgcn_mfma_f32_16x16x32_bf16(af[kk], bf[ss][kk], acc, 0,0,0); \
      float v0 = acc[0], v1 = acc[1], v2 = acc[2], v3 = acc[3]; \
      if (jb == awave + ss*16){ \
        int r0 = lg*4; \
        if (r0+0 == ln) v0 = -INFINITY; \
        if (r0+1 == ln) v1 = -INFINITY; \
        if (r0+2 == ln) v2 = -INFINITY; \
        if (r0+3 == ln) v3 = -INFINITY; \
      } \
      rm[ss] = fmaxf(rm[ss], fmaxf(fmaxf(v0,v1), fmaxf(v2,v3))); \
    } }
  LOADA(afA, 0);
  for (int tt = 0; tt < NTT; tt += 2){
    LOADA(afB, tt+1);
    CMAX(afA, tt);
    if (tt+2 < NTT) LOADA(afA, tt+2);
    CMAX(afB, tt+1);
  }
#undef LOADA
#undef CMAX
  #pragma unroll
  for (int ss = 0; ss < 4; ss++){
    float mm = rm[ss];
    mm = fmaxf(mm, __shfl_xor(mm, 16));
    mm = fmaxf(mm, __shfl_xor(mm, 32));
    if (lane < 16) atomicMax(&rmax[awave + ss*16 + lane], fkey(mm));
  }
}

// pass B: exp-sum with fixed per-anchor m. grid (32 anchorblk, 32 split)
__global__ __launch_bounds__(256) void k_lseB(const unsigned short* __restrict__ zbf,
                                              const unsigned* __restrict__ rmax,
                                              float* __restrict__ part){
  const int t = threadIdx.x;
  const int wv = t>>6, lane = t&63;
  const int awave = blockIdx.x*256 + wv*64;
  const int split = blockIdx.y;
  const int j0 = split*JSPL;
  const int lg = lane>>4, ln = lane&15;

  short8v bf[4][4];
  #pragma unroll
  for (int ss = 0; ss < 4; ss++){
    const unsigned short* zr = zbf + (size_t)(awave + ss*16 + ln)*WD;
    #pragma unroll
    for (int kk = 0; kk < 4; kk++)
      bf[ss][kk] = *(const short8v*)(zr + kk*32 + lg*8);
  }
  float mf[4], l[4];
  #pragma unroll
  for (int ss = 0; ss < 4; ss++){
    mf[ss] = fkeyinv(rmax[awave + ss*16 + ln]);
    l[ss] = 0.f;
  }

  const unsigned short* ap = zbf + (size_t)(j0+ln)*WD + lg*8;
  short8v afA[4], afB[4];
#define LOADA(dst, tt) { const unsigned short* p_ = ap + (size_t)(tt)*16*WD; \
    dst[0] = *(const short8v*)(p_);      dst[1] = *(const short8v*)(p_+32);  \
    dst[2] = *(const short8v*)(p_+64);   dst[3] = *(const short8v*)(p_+96); }
#define CSUM(af, tt) { \
    const int jb = j0 + (tt)*16; \
    _Pragma("unroll") \
    for (int ss = 0; ss < 4; ss++){ \
      float4v acc = {0.f,0.f,0.f,0.f}; \
      _Pragma("unroll") \
      for (int kk = 0; kk < 4; kk++) \
        acc = __builtin_amdgcn_mfma_f32_16x16x32_bf16(af[kk], bf[ss][kk], acc, 0,0,0); \
      float v0 = acc[0], v1 = acc[1], v2 = acc[2], v3 = acc[3]; \
      if (jb == awave + ss*16){ \
        int r0 = lg*4; \
        if (r0+0 == ln) v0 = -INFINITY; \
        if (r0+1 == ln) v1 = -INFINITY; \
        if (r0+2 == ln) v2 = -INFINITY; \
        if (r0+3 == ln) v3 = -INFINITY; \
      } \
      l[ss] += (EXP2(v0-mf[ss]) + EXP2(v1-mf[ss])) \
             + (EXP2(v2-mf[ss]) + EXP2(v3-mf[ss])); \
    } }
  LOADA(afA, 0);
  for (int tt = 0; tt < NTT; tt += 2){
    LOADA(afB, tt+1);
    CSUM(afA, tt);
    if (tt+2 < NTT) LOADA(afA, tt+2);
    CSUM(afB, tt+1);
  }
#undef LOADA
#undef CSUM
  #pragma unroll
  for (int ss = 0; ss < 4; ss++){
    float ll = l[ss];
    ll += __shfl_xor(ll, 16);
    ll += __shfl_xor(ll, 32);
    if (lane < 16)
      part[(size_t)split*WB + awave + ss*16 + lane] = ll;
  }
}

__global__ __launch_bounds__(256) void k_final(const float* __restrict__ z,
                                               const int* __restrict__ labels,
                                               const float* __restrict__ S,
                                               const int* __restrict__ cnt,
                                               const unsigned* __restrict__ rmax,
                                               const float* __restrict__ part,
                                               float* accf, int* accn, int* ticket,
                                               float* __restrict__ out){
  int i = blockIdx.x*256 + threadIdx.x;
  float lsum = 0.f;
  #pragma unroll
  for (int sp = 0; sp < NSPLIT; sp++) lsum += part[(size_t)sp*WB + i];
  float m = fkeyinv(rmax[i]);
  float lse = (m + LOG2(lsum)) * LN2F;           // natural-log LSE
  int lab = labels[i];
  const float4* zi = (const float4*)(z + (size_t)i*WD);
  const float4* sc = (const float4*)(S + (size_t)lab*WD);
  float pd = 0.f, sd = 0.f;
  #pragma unroll 8
  for (int k = 0; k < WD/4; k++){
    float4 a = zi[k], b = sc[k];
    pd += a.x*b.x + a.y*b.y + a.z*b.z + a.w*b.w;
    sd += a.x*a.x + a.y*a.y + a.z*a.z + a.w*a.w;
  }
  int np = cnt[lab] - 1;
  float loss = 0.f, val = 0.f;
  if (np > 0){ loss = lse - (pd - sd)*10.0f/(float)np; val = 1.f; }
  #pragma unroll
  for (int off = 32; off > 0; off >>= 1){
    loss += __shfl_down(loss, off);
    val  += __shfl_down(val,  off);
  }
  __shared__ float sl[4], sv[4];
  int wv = threadIdx.x>>6, lane = threadIdx.x&63;
  if (lane == 0){ sl[wv] = loss; sv[wv] = val; }
  __syncthreads();
  if (threadIdx.x == 0){
    atomicAdd(accf, sl[0]+sl[1]+sl[2]+sl[3]);
    atomicAdd(accn, (int)(sv[0]+sv[1]+sv[2]+sv[3] + 0.5f));
    __threadfence();
    int tk = atomicAdd(ticket, 1);
    if (tk == (WB/256) - 1){                      // last block finalizes
      float f = atomicAdd(accf, 0.f);
      int   n = atomicAdd(accn, 0);
      out[0] = f / (float)max(n, 1);
    }
  }
}

extern "C" void kernel_launch(void* const* d_in, const int* in_sizes, int n_in,
                              void* d_out, int out_size, void* d_ws, size_t ws_size,
                              hipStream_t stream){
  const float* z = (const float*)d_in[0];
  const int* labels = (const int*)d_in[1];
  char* ws = (char*)d_ws;
  unsigned short* zbf = (unsigned short*)(ws + WS_ZBF);
  float* S      = (float*)(ws + WS_S);
  int*   cnt    = (int*)(ws + WS_CNT);
  int*   cntp   = (int*)(ws + WS_CNTP);
  float* accf   = (float*)(ws + WS_ACC);
  int*   accn   = (int*)(ws + WS_ACC + 4);
  int*   ticket = (int*)(ws + WS_ACC + 8);
  unsigned* rmax = (unsigned*)(ws + WS_RMAX);
  float* Spart  = (float*)(ws + WS_PART);
  float* part   = (float*)(ws + WS_PART);
  float* out = (float*)d_out;

  hipLaunchKernelGGL(k_prep,  dim3(512 + NCS),      dim3(256), 0, stream,
                     z, labels, zbf, Spart, cntp, rmax, accf, accn, ticket);
  hipLaunchKernelGGL(k_lseA,  dim3(1024 + 50),      dim3(256), 0, stream,
                     zbf, rmax, Spart, S, cntp, cnt);
  hipLaunchKernelGGL(k_lseB,  dim3(WB/256, NSPLIT), dim3(256), 0, stream,
                     zbf, rmax, part);
  hipLaunchKernelGGL(k_final, dim3(WB/256),         dim3(256), 0, stream,
                     z, labels, S, cnt, rmax, part, accf, accn, ticket, out);
}